// Round 7
// baseline (277.449 us; speedup 1.0000x reference)
//
#include <hip/hip_runtime.h>
#include <stdint.h>

#define N_ROWS 32768
#define K_CODES 1024
#define D_DIM 256
#define NELEM 8388608

// ws layout (proven <=1.45MB in prior rounds)
#define WS_COUNTS 0               // float[1024]
#define WS_ENORM 263168           // float[1024]
#define WS_ROWBEST_BYTES 1056768  // u64[32768]
#define WS_IDX_BYTES 1318912      // int[32768]

// out offsets (floats)
#define O_ZQ 0
#define O_LOSS 8388608
#define O_IDX 8388609
#define O_EMB 8421377
#define O_CS 8683521
#define O_EMAW 8684545

// scratch carved out of d_out:
//   Zp: seg-major fp16 [64 segs][32768 rows][16B] = bytes [0, 33554432)  (z_q_st region)
//   Ep: seg-major fp16 [64 segs][1024 rows][16B]  = 1 MB at EP_BYTE_OFF  (new_embedding region)
//   part: float [8][256][1024] = 8 MB, reuses bytes [0, 8388608) of the Zp region AFTER k_mm
#define EP_BYTE_OFF 33685520

typedef _Float16 half8 __attribute__((ext_vector_type(8)));
typedef float f32x16 __attribute__((ext_vector_type(16)));

__device__ __forceinline__ unsigned int fenc(float f) {
    unsigned int u = __float_as_uint(f);
    return (u & 0x80000000u) ? ~u : (u | 0x80000000u);
}
__device__ __forceinline__ unsigned long long umin64(unsigned long long a, unsigned long long b) {
    return a < b ? a : b;
}

__global__ __launch_bounds__(256) void k_init(float* ws) {
    int i = blockIdx.x * 256 + threadIdx.x;
    if (i < 1024) ws[i] = 0.0f;   // counts
    unsigned long long* rb = (unsigned long long*)((char*)ws + WS_ROWBEST_BYTES);
    if (i < N_ROWS) rb[i] = 0xFFFFFFFFFFFFFFFFull;
}

// emb (1024x256 f32) -> Ep seg-major [64 segs][1024][8 halfs], + enorm
__global__ __launch_bounds__(256) void k_conv_e(const float* __restrict__ emb,
                                                _Float16* __restrict__ Ep,
                                                float* __restrict__ enorm) {
    int k = blockIdx.x, d = threadIdx.x;
    float v = emb[k * 256 + d];
    _Float16 h = (_Float16)v;
    _Float16 l = (_Float16)(v - (float)h);
    int s = d >> 3, sub = d & 7;
    Ep[((size_t)s * 1024 + k) * 8 + sub] = h;
    Ep[((size_t)(32 + s) * 1024 + k) * 8 + sub] = l;
    float sq = v * v;
    #pragma unroll
    for (int off = 32; off >= 1; off >>= 1) sq += __shfl_down(sq, off, 64);
    __shared__ float red[4];
    if ((d & 63) == 0) red[d >> 6] = sq;
    __syncthreads();
    if (d == 0) enorm[k] = (red[0] + red[1]) + (red[2] + red[3]);
}

// z_e[b][d][hw] f32 -> Zp seg-major [64 segs][32768 rows][8 halfs]
__global__ __launch_bounds__(256) void k_conv_z(const float* __restrict__ z_e,
                                                _Float16* __restrict__ Zp) {
    __shared__ float lt[64 * 68];
    int t = threadIdx.x;
    int hw0 = blockIdx.x * 64, d0 = blockIdx.y * 64, b = blockIdx.z;
    const float* src = z_e + (size_t)b * 262144 + (size_t)d0 * 1024 + hw0;
    int dl = t >> 4, hl = (t & 15) * 4;
    #pragma unroll
    for (int i = 0; i < 4; i++) {
        int d = dl + i * 16;
        float4 v = *(const float4*)(src + (size_t)d * 1024 + hl);
        lt[(hl + 0) * 68 + d] = v.x;
        lt[(hl + 1) * 68 + d] = v.y;
        lt[(hl + 2) * 68 + d] = v.z;
        lt[(hl + 3) * 68 + d] = v.w;
    }
    __syncthreads();
    int hr = t >> 2, seg = t & 3;
    int n = b * 1024 + hw0 + hr;
    int sg0 = (d0 >> 3) + seg * 2;   // global hi-seg of first 8 halfs
    half8 hi[2], lo[2];
    #pragma unroll
    for (int p = 0; p < 2; p++) {
        #pragma unroll
        for (int j = 0; j < 8; j++) {
            float v = lt[hr * 68 + seg * 16 + p * 8 + j];
            _Float16 h = (_Float16)v;
            hi[p][j] = h;
            lo[p][j] = (_Float16)(v - (float)h);
        }
    }
    *(half8*)(Zp + ((size_t)(sg0 + 0) * 32768 + n) * 8) = hi[0];
    *(half8*)(Zp + ((size_t)(sg0 + 1) * 32768 + n) * 8) = hi[1];
    *(half8*)(Zp + ((size_t)(32 + sg0) * 32768 + n) * 8) = lo[0];
    *(half8*)(Zp + ((size_t)(33 + sg0) * 32768 + n) * 8) = lo[1];
}

// fp16-split distance GEMM, barrier-free: fragments loaded directly from
// global (seg-major layout = coalesced dwordx4 per fragment), MFMA<->load
// interleaved 1:1, no LDS. Transposed: A=codes (E), B=z-rows (Z), so
// D[code][zrow] puts each zrow in one lane column -> in-register argmin.
// Wave = 64 codes x 64 zrows; block = 4 waves (256 zrows); grid 128rt x 16ct.
__global__ __launch_bounds__(256) void k_mm(const _Float16* __restrict__ Zp,
                                            const _Float16* __restrict__ Ep,
                                            const float* __restrict__ enorm,
                                            unsigned long long* __restrict__ row_best) {
    int t = threadIdx.x;
    int lane = t & 63, wv = t >> 6;
    int b = blockIdx.x;
    int rt = (b & 7) + ((b >> 7) << 3);   // same-Z blocks -> same XCD (%8 round-robin)
    int ct = (b >> 3) & 15;
    int row0 = rt * 256 + wv * 64;        // this wave's 64 z-rows
    int code0 = ct * 64;
    int m31 = lane & 31, ko = lane >> 5;

    // per-lane fragment base pointers (seg = +ko)
    const char* ebase = (const char*)Ep + ((size_t)ko * 1024 + code0 + m31) * 16;
    const char* zbase = (const char*)Zp + ((size_t)ko * 32768 + row0 + m31) * 16;

    // term schedule: c 0..3 zh.eh, 4..7 zl.eh, 8..11 zh.el (seg bases)
    constexpr int ZB[12] = {0, 8, 16, 24, 32, 40, 48, 56, 0, 8, 16, 24};
    constexpr int EB[12] = {0, 8, 16, 24, 0, 8, 16, 24, 32, 40, 48, 56};

    f32x16 acc[2][2];   // [mt code-tile][nt zrow-tile]
    #pragma unroll
    for (int i = 0; i < 2; i++)
        #pragma unroll
        for (int j = 0; j < 2; j++)
            #pragma unroll
            for (int r = 0; r < 16; r++) acc[i][j][r] = 0.0f;

#define LDA(c, s, mt) (*(const half8*)(ebase + (((size_t)(EB[c] + 2 * (s))) * 1024 + (mt) * 32) * 16))
#define LDB(c, s, nt) (*(const half8*)(zbase + (((size_t)(ZB[c] + 2 * (s))) * 32768 + (nt) * 32) * 16))

    half8 a0 = LDA(0, 0, 0), a1 = LDA(0, 0, 1);
    half8 b0 = LDB(0, 0, 0), b1 = LDB(0, 0, 1);
    #pragma unroll
    for (int i = 0; i < 48; i++) {
        half8 na0, na1, nb0, nb1;
        if (i < 47) {
            int c2 = (i + 1) >> 2, s2 = (i + 1) & 3;
            na0 = LDA(c2, s2, 0); na1 = LDA(c2, s2, 1);
            nb0 = LDB(c2, s2, 0); nb1 = LDB(c2, s2, 1);
        }
        acc[0][0] = __builtin_amdgcn_mfma_f32_32x32x16_f16(a0, b0, acc[0][0], 0, 0, 0);
        acc[0][1] = __builtin_amdgcn_mfma_f32_32x32x16_f16(a0, b1, acc[0][1], 0, 0, 0);
        acc[1][0] = __builtin_amdgcn_mfma_f32_32x32x16_f16(a1, b0, acc[1][0], 0, 0, 0);
        acc[1][1] = __builtin_amdgcn_mfma_f32_32x32x16_f16(a1, b1, acc[1][1], 0, 0, 0);
        a0 = na0; a1 = na1; b0 = nb0; b1 = nb1;
    }
#undef LDA
#undef LDB

    // epilogue: D row=code=(reg&3)+8*(reg>>2)+4*ko+mt*32, col=zrow=nt*32+m31
    float en_a[32];
    #pragma unroll
    for (int mt = 0; mt < 2; mt++)
        #pragma unroll
        for (int r = 0; r < 16; r++)
            en_a[mt * 16 + r] = enorm[code0 + mt * 32 + 4 * ko + (r & 3) + 8 * (r >> 2)];

    #pragma unroll
    for (int nt = 0; nt < 2; nt++) {
        unsigned long long best = 0xFFFFFFFFFFFFFFFFull;
        #pragma unroll
        for (int mt = 0; mt < 2; mt++)
            #pragma unroll
            for (int r = 0; r < 16; r++) {
                unsigned int code = code0 + mt * 32 + 4 * ko + (r & 3) + 8 * (r >> 2);
                float dist = en_a[mt * 16 + r] - 2.0f * acc[mt][nt][r];
                unsigned long long pk = ((unsigned long long)fenc(dist) << 32) | code;
                best = umin64(best, pk);
            }
        best = umin64(best, __shfl_xor(best, 32, 64));
        if (ko == 0) atomicMin(&row_best[row0 + nt * 32 + m31], best);
    }
}

__global__ __launch_bounds__(256) void k_fin_idx(const unsigned long long* __restrict__ rb,
                                                 int* __restrict__ idxs, float* __restrict__ out) {
    int i = blockIdx.x * 256 + threadIdx.x;
    if (i < N_ROWS) {
        int id = (int)(rb[i] & 0xFFFFFFFFull);
        idxs[i] = id;
        out[O_IDX + i] = (float)id;
    }
}

__global__ __launch_bounds__(256) void k_counts(const int* __restrict__ idxs,
                                                float* __restrict__ counts) {
    __shared__ float hist[K_CODES];
    int t = threadIdx.x;
    #pragma unroll
    for (int j = 0; j < 4; j++) hist[j * 256 + t] = 0.0f;
    __syncthreads();
    int n0 = blockIdx.x * 1024;
    #pragma unroll
    for (int i = 0; i < 4; i++) {
        int id = idxs[n0 + i * 256 + t];
        atomicAdd(&hist[id], 1.0f);
    }
    __syncthreads();
    #pragma unroll
    for (int j = 0; j < 4; j++) {
        float h = hist[j * 256 + t];
        if (h != 0.0f) atomicAdd(&counts[j * 256 + t], h);
    }
}

// dw partial segment-sum: block (s-chunk, d). float4/int4 loads, LDS acc[1024],
// flush as PLAIN coalesced stores to part[s][d][1024] (no global atomics).
__global__ __launch_bounds__(256) void k_dw(const float* __restrict__ z_e,
                                            const int* __restrict__ idxs,
                                            float* __restrict__ part) {
    __shared__ float acc[K_CODES];
    int t = threadIdx.x;
    int s = blockIdx.x;   // 0..7
    int d = blockIdx.y;   // 0..255
    #pragma unroll
    for (int j = 0; j < 4; j++) acc[j * 256 + t] = 0.0f;
    __syncthreads();
    #pragma unroll
    for (int i = 0; i < 4; i++) {
        int b = s * 4 + i;
        int4 id4 = *(const int4*)(idxs + b * 1024 + t * 4);
        float4 v = *(const float4*)(z_e + (size_t)b * 262144 + (size_t)d * 1024 + t * 4);
        atomicAdd(&acc[id4.x], v.x);
        atomicAdd(&acc[id4.y], v.y);
        atomicAdd(&acc[id4.z], v.z);
        atomicAdd(&acc[id4.w], v.w);
    }
    __syncthreads();
    float* pr = part + ((size_t)s * 256 + d) * 1024;
    #pragma unroll
    for (int j = 0; j < 4; j++) pr[j * 256 + t] = acc[j * 256 + t];
}

// reduce 8 partials + EMA finalize. block = 64-code x 64-d tile.
__global__ __launch_bounds__(256) void k_red(const float* __restrict__ part,
                                             const float* __restrict__ ema_cs,
                                             const float* __restrict__ ema_w,
                                             const float* __restrict__ counts,
                                             float* __restrict__ out) {
    __shared__ float tile[64 * 69];   // [d][k], pad 69
    __shared__ float csl[64];
    int t = threadIdx.x;
    int k0 = blockIdx.x * 64, d0 = blockIdx.y * 64;
    int dr = t >> 4, kc = t & 15;
    float4 sum[4] = {};
    for (int s = 0; s < 8; s++) {
        const float* pb = part + ((size_t)s * 256 + d0) * 1024 + k0 + kc * 4;
        #pragma unroll
        for (int q = 0; q < 4; q++) {
            float4 v = *(const float4*)(pb + (size_t)(dr + 16 * q) * 1024);
            sum[q].x += v.x; sum[q].y += v.y; sum[q].z += v.z; sum[q].w += v.w;
        }
    }
    if (t < 64) csl[t] = 0.99f * ema_cs[k0 + t] + 0.01f * counts[k0 + t];
    #pragma unroll
    for (int q = 0; q < 4; q++) {
        float* p = tile + (dr + 16 * q) * 69 + kc * 4;
        p[0] = sum[q].x; p[1] = sum[q].y; p[2] = sum[q].z; p[3] = sum[q].w;
    }
    __syncthreads();
    int kk = t >> 2, dq = t & 3;
    int k = k0 + kk;
    float inv = 1.0f / (csl[kk] + 1e-5f);
    #pragma unroll
    for (int j4 = 0; j4 < 4; j4++) {
        int dd = dq * 16 + j4 * 4;
        size_t kd = (size_t)k * 256 + d0 + dd;
        float4 w = *(const float4*)(ema_w + kd);
        float4 nw;
        nw.x = 0.99f * w.x + 0.01f * tile[(dd + 0) * 69 + kk];
        nw.y = 0.99f * w.y + 0.01f * tile[(dd + 1) * 69 + kk];
        nw.z = 0.99f * w.z + 0.01f * tile[(dd + 2) * 69 + kk];
        nw.w = 0.99f * w.w + 0.01f * tile[(dd + 3) * 69 + kk];
        *(float4*)(out + O_EMAW + kd) = nw;
        float4 ne = {nw.x * inv, nw.y * inv, nw.z * inv, nw.w * inv};
        *(float4*)(out + O_EMB + kd) = ne;
    }
    if (blockIdx.y == 0 && t < 64) out[O_CS + k0 + t] = csl[t];
    if (blockIdx.x == 0 && blockIdx.y == 0 && t == 0) out[O_LOSS] = 0.0f;
}

// tiled transpose-gather: block = 64 hw x 64 d.
__global__ __launch_bounds__(256) void k_gather(const float* __restrict__ z_e,
                                                const int* __restrict__ idxs,
                                                float* __restrict__ out) {
    __shared__ float lt[64 * 68];
    __shared__ int sid[64];
    __shared__ float red[4];
    int t = threadIdx.x;
    int hw0 = blockIdx.x * 64, d0 = blockIdx.y * 64, b = blockIdx.z;
    if (t < 64) sid[t] = idxs[b * 1024 + hw0 + t];
    const float* src = z_e + (size_t)b * 262144 + (size_t)d0 * 1024 + hw0;
    int dl = t >> 4, hl = (t & 15) * 4;
    #pragma unroll
    for (int i = 0; i < 4; i++) {
        int d = dl + i * 16;
        float4 v = *(const float4*)(src + (size_t)d * 1024 + hl);
        lt[(hl + 0) * 68 + d] = v.x;
        lt[(hl + 1) * 68 + d] = v.y;
        lt[(hl + 2) * 68 + d] = v.z;
        lt[(hl + 3) * 68 + d] = v.w;
    }
    __syncthreads();
    int r = t >> 2, c = t & 3;
    const float* nrow = out + O_EMB + (size_t)sid[r] * 256 + d0;
    float lacc = 0.0f;
    #pragma unroll
    for (int it = 0; it < 4; it++) {
        int dd = it * 16 + c * 4;
        float4 q = *(const float4*)(nrow + dd);
        float* p = lt + r * 68 + dd;
        float z0 = p[0], z1 = p[1], z2 = p[2], z3 = p[3];
        p[0] = z0 + (q.x - z0);
        p[1] = z1 + (q.y - z1);
        p[2] = z2 + (q.z - z2);
        p[3] = z3 + (q.w - z3);
        float dx = z0 - q.x, dy = z1 - q.y, dz = z2 - q.z, dw4 = z3 - q.w;
        lacc += dx * dx + dy * dy + dz * dz + dw4 * dw4;
    }
    __syncthreads();
    float* dst = out + O_ZQ + (size_t)b * 262144 + (size_t)d0 * 1024 + hw0;
    #pragma unroll
    for (int i = 0; i < 4; i++) {
        int d = dl + i * 16;
        float4 w;
        w.x = lt[(hl + 0) * 68 + d];
        w.y = lt[(hl + 1) * 68 + d];
        w.z = lt[(hl + 2) * 68 + d];
        w.w = lt[(hl + 3) * 68 + d];
        *(float4*)(dst + (size_t)d * 1024 + hl) = w;
    }
    #pragma unroll
    for (int off = 32; off >= 1; off >>= 1) lacc += __shfl_down(lacc, off, 64);
    int lane = t & 63, wv = t >> 6;
    if (lane == 0) red[wv] = lacc;
    __syncthreads();
    if (t == 0) {
        float s = (red[0] + red[1]) + (red[2] + red[3]);
        atomicAdd(out + O_LOSS, s * 2.9802322387695312e-08f); // * BETA / NELEM
    }
}

extern "C" void kernel_launch(void* const* d_in, const int* in_sizes, int n_in,
                              void* d_out, int out_size, void* d_ws, size_t ws_size,
                              hipStream_t stream) {
    const float* z_e = (const float*)d_in[0];
    const float* emb = (const float*)d_in[1];
    const float* ema_cs = (const float*)d_in[2];
    const float* ema_w = (const float*)d_in[3];
    float* out = (float*)d_out;
    float* ws = (float*)d_ws;

    float* counts = ws + WS_COUNTS;
    float* enorm = ws + WS_ENORM;
    unsigned long long* row_best = (unsigned long long*)((char*)d_ws + WS_ROWBEST_BYTES);
    int* idxs = (int*)((char*)d_ws + WS_IDX_BYTES);

    _Float16* Zp = (_Float16*)d_out;                        // dead after k_mm
    _Float16* Ep = (_Float16*)((char*)d_out + EP_BYTE_OFF); // dead after k_red
    float* part = (float*)d_out;                            // 8 MB, reuses Zp region after k_mm

    k_init<<<128, 256, 0, stream>>>(ws);
    k_conv_e<<<1024, 256, 0, stream>>>(emb, Ep, enorm);
    k_conv_z<<<dim3(16, 4, 32), 256, 0, stream>>>(z_e, Zp);
    k_mm<<<2048, 256, 0, stream>>>(Zp, Ep, enorm, row_best);
    k_fin_idx<<<128, 256, 0, stream>>>(row_best, idxs, out);
    k_counts<<<32, 256, 0, stream>>>(idxs, counts);
    k_dw<<<dim3(8, 256), 256, 0, stream>>>(z_e, idxs, part);
    k_red<<<dim3(16, 4), 256, 0, stream>>>(part, ema_cs, ema_w, counts, out);
    k_gather<<<dim3(16, 4, 32), 256, 0, stream>>>(z_e, idxs, out);
}

// Round 8
// 255.688 us; speedup vs baseline: 1.0851x; 1.0851x over previous
//
#include <hip/hip_runtime.h>
#include <stdint.h>

#define N_ROWS 32768
#define K_CODES 1024
#define D_DIM 256
#define NELEM 8388608

// ws layout (proven <=1.45MB in prior rounds)
#define WS_COUNTS 0               // float[1024]
#define WS_ENORM 263168           // float[1024]
#define WS_ROWBEST_BYTES 1056768  // u64[32768]
#define WS_IDX_BYTES 1318912      // int[32768]

// out offsets (floats)
#define O_ZQ 0
#define O_LOSS 8388608
#define O_IDX 8388609
#define O_EMB 8421377
#define O_CS 8683521
#define O_EMAW 8684545

// scratch carved out of d_out:
//   Zp: seg-major fp16 [64 segs][32768 rows][16B] = bytes [0, 33554432)  (z_q_st region)
//   Ep: seg-major fp16 [64 segs][1024 rows][16B]  = 1 MB at EP_BYTE_OFF  (new_embedding region)
//   part: float [8][256][1024] = 8 MB, reuses bytes [0, 8388608) of the Zp region AFTER k_mm
#define EP_BYTE_OFF 33685520

typedef _Float16 half8 __attribute__((ext_vector_type(8)));
typedef float f32x16 __attribute__((ext_vector_type(16)));

__device__ __forceinline__ unsigned int fenc(float f) {
    unsigned int u = __float_as_uint(f);
    return (u & 0x80000000u) ? ~u : (u | 0x80000000u);
}
__device__ __forceinline__ unsigned long long umin64(unsigned long long a, unsigned long long b) {
    return a < b ? a : b;
}
__device__ __forceinline__ void gll16(const void* g, void* l) {
    __builtin_amdgcn_global_load_lds((const __attribute__((address_space(1))) void*)g,
                                     (__attribute__((address_space(3))) void*)l, 16, 0, 0);
}

__global__ __launch_bounds__(256) void k_init(float* ws) {
    int i = blockIdx.x * 256 + threadIdx.x;
    if (i < 1024) ws[i] = 0.0f;   // counts
    unsigned long long* rb = (unsigned long long*)((char*)ws + WS_ROWBEST_BYTES);
    if (i < N_ROWS) rb[i] = 0xFFFFFFFFFFFFFFFFull;
}

// emb (1024x256 f32) -> Ep seg-major [64 segs][1024][8 halfs], + enorm
__global__ __launch_bounds__(256) void k_conv_e(const float* __restrict__ emb,
                                                _Float16* __restrict__ Ep,
                                                float* __restrict__ enorm) {
    int k = blockIdx.x, d = threadIdx.x;
    float v = emb[k * 256 + d];
    _Float16 h = (_Float16)v;
    _Float16 l = (_Float16)(v - (float)h);
    int s = d >> 3, sub = d & 7;
    Ep[((size_t)s * 1024 + k) * 8 + sub] = h;
    Ep[((size_t)(32 + s) * 1024 + k) * 8 + sub] = l;
    float sq = v * v;
    #pragma unroll
    for (int off = 32; off >= 1; off >>= 1) sq += __shfl_down(sq, off, 64);
    __shared__ float red[4];
    if ((d & 63) == 0) red[d >> 6] = sq;
    __syncthreads();
    if (d == 0) enorm[k] = (red[0] + red[1]) + (red[2] + red[3]);
}

// z_e[b][d][hw] f32 -> Zp seg-major [64 segs][32768 rows][8 halfs]
__global__ __launch_bounds__(256) void k_conv_z(const float* __restrict__ z_e,
                                                _Float16* __restrict__ Zp) {
    __shared__ float lt[64 * 68];
    int t = threadIdx.x;
    int hw0 = blockIdx.x * 64, d0 = blockIdx.y * 64, b = blockIdx.z;
    const float* src = z_e + (size_t)b * 262144 + (size_t)d0 * 1024 + hw0;
    int dl = t >> 4, hl = (t & 15) * 4;
    #pragma unroll
    for (int i = 0; i < 4; i++) {
        int d = dl + i * 16;
        float4 v = *(const float4*)(src + (size_t)d * 1024 + hl);
        lt[(hl + 0) * 68 + d] = v.x;
        lt[(hl + 1) * 68 + d] = v.y;
        lt[(hl + 2) * 68 + d] = v.z;
        lt[(hl + 3) * 68 + d] = v.w;
    }
    __syncthreads();
    int hr = t >> 2, seg = t & 3;
    int n = b * 1024 + hw0 + hr;
    int sg0 = (d0 >> 3) + seg * 2;   // global hi-seg of first 8 halfs
    half8 hi[2], lo[2];
    #pragma unroll
    for (int p = 0; p < 2; p++) {
        #pragma unroll
        for (int j = 0; j < 8; j++) {
            float v = lt[hr * 68 + seg * 16 + p * 8 + j];
            _Float16 h = (_Float16)v;
            hi[p][j] = h;
            lo[p][j] = (_Float16)(v - (float)h);
        }
    }
    *(half8*)(Zp + ((size_t)(sg0 + 0) * 32768 + n) * 8) = hi[0];
    *(half8*)(Zp + ((size_t)(sg0 + 1) * 32768 + n) * 8) = hi[1];
    *(half8*)(Zp + ((size_t)(32 + sg0) * 32768 + n) * 8) = lo[0];
    *(half8*)(Zp + ((size_t)(33 + sg0) * 32768 + n) * 8) = lo[1];
}

// fused fp16-split GEMM (3 terms: zh.eh + zl.eh + zh.el) + argmin epilogue.
// block tile 128x128, 4 waves 64x64, mfma 32x32x16 f16, K=64/iter, 12 iters,
// LDS DOUBLE-BUFFERED: stage(c+1) issued before compute(c), one barrier/iter.
__global__ __launch_bounds__(256) void k_mm(const _Float16* __restrict__ Zp,
                                            const _Float16* __restrict__ Ep,
                                            const float* __restrict__ enorm,
                                            unsigned long long* __restrict__ row_best) {
    __shared__ __align__(16) char smem[65536];   // 2 x (Za 16KB + Ea 16KB)
    unsigned long long* slot = (unsigned long long*)smem; // [128][32] after loop

    int t = threadIdx.x;
    int lane = t & 63, wv = t >> 6;
    int b = blockIdx.x;
    int rt = (b & 7) + ((b >> 6) << 3);   // same-Z blocks -> same XCD (assumes %8 round-robin)
    int ct = (b >> 3) & 7;
    int row0 = rt * 128, code0 = ct * 128;

    int wr = wv >> 1, wc = wv & 1;
    int m31 = lane & 31, ko = lane >> 5;

    f32x16 acc[2][2];
    #pragma unroll
    for (int i = 0; i < 2; i++)
        #pragma unroll
        for (int j = 0; j < 2; j++)
            #pragma unroll
            for (int r = 0; r < 16; r++) acc[i][j][r] = 0.0f;

    // staging: wave wv stages segs {2wv, 2wv+1}; lane l -> row l (+64 for 2nd call)
    const char* zgl = (const char*)Zp + ((size_t)(2 * wv) * 32768 + row0 + lane) * 16;
    const char* egl = (const char*)Ep + ((size_t)(2 * wv) * 1024 + code0 + lane) * 16;
    const int ldoff = 2 * wv * 1024;

    auto stage = [&](int c, char* base) {
        int kz = (c < 8) ? c : (c - 8);                                      // Z 64-half group
        int ge = (c < 4) ? c * 8 : (c < 8) ? (c - 4) * 8 : 32 + (c - 8) * 8; // E seg base
        const char* zg = zgl + (size_t)kz * 8 * 32768 * 16;
        const char* eg = egl + (size_t)ge * 1024 * 16;
        _Float16* zld = (_Float16*)base + ldoff;
        _Float16* eld = (_Float16*)(base + 16384) + ldoff;
        gll16(zg, zld);
        gll16(zg + 64 * 16, zld + 512);
        gll16(zg + 32768 * 16, zld + 1024);
        gll16(zg + 32768 * 16 + 64 * 16, zld + 1536);
        gll16(eg, eld);
        gll16(eg + 64 * 16, eld + 512);
        gll16(eg + 1024 * 16, eld + 1024);
        gll16(eg + 1024 * 16 + 64 * 16, eld + 1536);
    };

    stage(0, smem);
    __syncthreads();

    for (int c = 0; c < 12; c++) {
        char* cur = smem + (size_t)(c & 1) * 32768;
        if (c < 11) stage(c + 1, smem + (size_t)((c + 1) & 1) * 32768);
        _Float16* Za = (_Float16*)cur;
        _Float16* Ea = (_Float16*)(cur + 16384);
        #pragma unroll
        for (int ks = 0; ks < 4; ks++) {
            int sseg = 2 * ks + ko;
            half8 a0 = *(const half8*)(Za + sseg * 1024 + (wr * 64 + m31) * 8);
            half8 a1 = *(const half8*)(Za + sseg * 1024 + (wr * 64 + 32 + m31) * 8);
            half8 b0 = *(const half8*)(Ea + sseg * 1024 + (wc * 64 + m31) * 8);
            half8 b1 = *(const half8*)(Ea + sseg * 1024 + (wc * 64 + 32 + m31) * 8);
            acc[0][0] = __builtin_amdgcn_mfma_f32_32x32x16_f16(a0, b0, acc[0][0], 0, 0, 0);
            acc[0][1] = __builtin_amdgcn_mfma_f32_32x32x16_f16(a0, b1, acc[0][1], 0, 0, 0);
            acc[1][0] = __builtin_amdgcn_mfma_f32_32x32x16_f16(a1, b0, acc[1][0], 0, 0, 0);
            acc[1][1] = __builtin_amdgcn_mfma_f32_32x32x16_f16(a1, b1, acc[1][1], 0, 0, 0);
        }
        __syncthreads();   // drains c+1 staging (overlapped by the MFMAs above)
    }

    // epilogue: dist = ||e||^2 - 2*dot
    // C/D 32x32 layout: col=lane&31, row=(reg&3)+8*(reg>>2)+4*(lane>>5)
    float en0 = enorm[code0 + wc * 64 + m31];
    float en1 = enorm[code0 + wc * 64 + 32 + m31];
    unsigned int col0 = code0 + wc * 64 + m31;
    unsigned int col1 = col0 + 32;

    if (wc == 0) {
        #pragma unroll
        for (int mt = 0; mt < 2; mt++)
            #pragma unroll
            for (int j = 0; j < 16; j++) {
                int row = wr * 64 + mt * 32 + 4 * ko + (j & 3) + 8 * (j >> 2);
                unsigned long long p0 = ((unsigned long long)fenc(en0 - 2.0f * acc[mt][0][j]) << 32) | col0;
                unsigned long long p1 = ((unsigned long long)fenc(en1 - 2.0f * acc[mt][1][j]) << 32) | col1;
                slot[row * 32 + ((m31 + row) & 31)] = umin64(p0, p1);
            }
    }
    __syncthreads();
    if (wc == 1) {
        #pragma unroll
        for (int mt = 0; mt < 2; mt++)
            #pragma unroll
            for (int j = 0; j < 16; j++) {
                int row = wr * 64 + mt * 32 + 4 * ko + (j & 3) + 8 * (j >> 2);
                unsigned long long p0 = ((unsigned long long)fenc(en0 - 2.0f * acc[mt][0][j]) << 32) | col0;
                unsigned long long p1 = ((unsigned long long)fenc(en1 - 2.0f * acc[mt][1][j]) << 32) | col1;
                atomicMin(&slot[row * 32 + ((m31 + row) & 31)], umin64(p0, p1));
            }
    }
    __syncthreads();
    if (t < 128) {
        unsigned long long m = slot[t * 32 + (t & 31)];
        #pragma unroll
        for (int i = 1; i < 32; i++) m = umin64(m, slot[t * 32 + ((i + t) & 31)]);
        atomicMin(&row_best[row0 + t], m);
    }
}

__global__ __launch_bounds__(256) void k_fin_idx(const unsigned long long* __restrict__ rb,
                                                 int* __restrict__ idxs, float* __restrict__ out) {
    int i = blockIdx.x * 256 + threadIdx.x;
    if (i < N_ROWS) {
        int id = (int)(rb[i] & 0xFFFFFFFFull);
        idxs[i] = id;
        out[O_IDX + i] = (float)id;
    }
}

__global__ __launch_bounds__(256) void k_counts(const int* __restrict__ idxs,
                                                float* __restrict__ counts) {
    __shared__ float hist[K_CODES];
    int t = threadIdx.x;
    #pragma unroll
    for (int j = 0; j < 4; j++) hist[j * 256 + t] = 0.0f;
    __syncthreads();
    int n0 = blockIdx.x * 1024;
    #pragma unroll
    for (int i = 0; i < 4; i++) {
        int id = idxs[n0 + i * 256 + t];
        atomicAdd(&hist[id], 1.0f);
    }
    __syncthreads();
    #pragma unroll
    for (int j = 0; j < 4; j++) {
        float h = hist[j * 256 + t];
        if (h != 0.0f) atomicAdd(&counts[j * 256 + t], h);
    }
}

// dw partial segment-sum: block (s-chunk, d). float4/int4 loads, LDS acc[1024],
// flush as PLAIN coalesced stores to part[s][d][1024] (no global atomics).
__global__ __launch_bounds__(256) void k_dw(const float* __restrict__ z_e,
                                            const int* __restrict__ idxs,
                                            float* __restrict__ part) {
    __shared__ float acc[K_CODES];
    int t = threadIdx.x;
    int s = blockIdx.x;   // 0..7
    int d = blockIdx.y;   // 0..255
    #pragma unroll
    for (int j = 0; j < 4; j++) acc[j * 256 + t] = 0.0f;
    __syncthreads();
    #pragma unroll
    for (int i = 0; i < 4; i++) {
        int b = s * 4 + i;
        int4 id4 = *(const int4*)(idxs + b * 1024 + t * 4);
        float4 v = *(const float4*)(z_e + (size_t)b * 262144 + (size_t)d * 1024 + t * 4);
        atomicAdd(&acc[id4.x], v.x);
        atomicAdd(&acc[id4.y], v.y);
        atomicAdd(&acc[id4.z], v.z);
        atomicAdd(&acc[id4.w], v.w);
    }
    __syncthreads();
    float* pr = part + ((size_t)s * 256 + d) * 1024;
    #pragma unroll
    for (int j = 0; j < 4; j++) pr[j * 256 + t] = acc[j * 256 + t];
}

// reduce 8 partials + EMA finalize. block = 64-code x 64-d tile.
__global__ __launch_bounds__(256) void k_red(const float* __restrict__ part,
                                             const float* __restrict__ ema_cs,
                                             const float* __restrict__ ema_w,
                                             const float* __restrict__ counts,
                                             float* __restrict__ out) {
    __shared__ float tile[64 * 69];   // [d][k], pad 69
    __shared__ float csl[64];
    int t = threadIdx.x;
    int k0 = blockIdx.x * 64, d0 = blockIdx.y * 64;
    int dr = t >> 4, kc = t & 15;
    float4 sum[4] = {};
    for (int s = 0; s < 8; s++) {
        const float* pb = part + ((size_t)s * 256 + d0) * 1024 + k0 + kc * 4;
        #pragma unroll
        for (int q = 0; q < 4; q++) {
            float4 v = *(const float4*)(pb + (size_t)(dr + 16 * q) * 1024);
            sum[q].x += v.x; sum[q].y += v.y; sum[q].z += v.z; sum[q].w += v.w;
        }
    }
    if (t < 64) csl[t] = 0.99f * ema_cs[k0 + t] + 0.01f * counts[k0 + t];
    #pragma unroll
    for (int q = 0; q < 4; q++) {
        float* p = tile + (dr + 16 * q) * 69 + kc * 4;
        p[0] = sum[q].x; p[1] = sum[q].y; p[2] = sum[q].z; p[3] = sum[q].w;
    }
    __syncthreads();
    int kk = t >> 2, dq = t & 3;
    int k = k0 + kk;
    float inv = 1.0f / (csl[kk] + 1e-5f);
    #pragma unroll
    for (int j4 = 0; j4 < 4; j4++) {
        int dd = dq * 16 + j4 * 4;
        size_t kd = (size_t)k * 256 + d0 + dd;
        float4 w = *(const float4*)(ema_w + kd);
        float4 nw;
        nw.x = 0.99f * w.x + 0.01f * tile[(dd + 0) * 69 + kk];
        nw.y = 0.99f * w.y + 0.01f * tile[(dd + 1) * 69 + kk];
        nw.z = 0.99f * w.z + 0.01f * tile[(dd + 2) * 69 + kk];
        nw.w = 0.99f * w.w + 0.01f * tile[(dd + 3) * 69 + kk];
        *(float4*)(out + O_EMAW + kd) = nw;
        float4 ne = {nw.x * inv, nw.y * inv, nw.z * inv, nw.w * inv};
        *(float4*)(out + O_EMB + kd) = ne;
    }
    if (blockIdx.y == 0 && t < 64) out[O_CS + k0 + t] = csl[t];
    if (blockIdx.x == 0 && blockIdx.y == 0 && t == 0) out[O_LOSS] = 0.0f;
}

// tiled transpose-gather: block = 64 hw x 64 d.
__global__ __launch_bounds__(256) void k_gather(const float* __restrict__ z_e,
                                                const int* __restrict__ idxs,
                                                float* __restrict__ out) {
    __shared__ float lt[64 * 68];
    __shared__ int sid[64];
    __shared__ float red[4];
    int t = threadIdx.x;
    int hw0 = blockIdx.x * 64, d0 = blockIdx.y * 64, b = blockIdx.z;
    if (t < 64) sid[t] = idxs[b * 1024 + hw0 + t];
    const float* src = z_e + (size_t)b * 262144 + (size_t)d0 * 1024 + hw0;
    int dl = t >> 4, hl = (t & 15) * 4;
    #pragma unroll
    for (int i = 0; i < 4; i++) {
        int d = dl + i * 16;
        float4 v = *(const float4*)(src + (size_t)d * 1024 + hl);
        lt[(hl + 0) * 68 + d] = v.x;
        lt[(hl + 1) * 68 + d] = v.y;
        lt[(hl + 2) * 68 + d] = v.z;
        lt[(hl + 3) * 68 + d] = v.w;
    }
    __syncthreads();
    int r = t >> 2, c = t & 3;
    const float* nrow = out + O_EMB + (size_t)sid[r] * 256 + d0;
    float lacc = 0.0f;
    #pragma unroll
    for (int it = 0; it < 4; it++) {
        int dd = it * 16 + c * 4;
        float4 q = *(const float4*)(nrow + dd);
        float* p = lt + r * 68 + dd;
        float z0 = p[0], z1 = p[1], z2 = p[2], z3 = p[3];
        p[0] = z0 + (q.x - z0);
        p[1] = z1 + (q.y - z1);
        p[2] = z2 + (q.z - z2);
        p[3] = z3 + (q.w - z3);
        float dx = z0 - q.x, dy = z1 - q.y, dz = z2 - q.z, dw4 = z3 - q.w;
        lacc += dx * dx + dy * dy + dz * dz + dw4 * dw4;
    }
    __syncthreads();
    float* dst = out + O_ZQ + (size_t)b * 262144 + (size_t)d0 * 1024 + hw0;
    #pragma unroll
    for (int i = 0; i < 4; i++) {
        int d = dl + i * 16;
        float4 w;
        w.x = lt[(hl + 0) * 68 + d];
        w.y = lt[(hl + 1) * 68 + d];
        w.z = lt[(hl + 2) * 68 + d];
        w.w = lt[(hl + 3) * 68 + d];
        *(float4*)(dst + (size_t)d * 1024 + hl) = w;
    }
    #pragma unroll
    for (int off = 32; off >= 1; off >>= 1) lacc += __shfl_down(lacc, off, 64);
    int lane = t & 63, wv = t >> 6;
    if (lane == 0) red[wv] = lacc;
    __syncthreads();
    if (t == 0) {
        float s = (red[0] + red[1]) + (red[2] + red[3]);
        atomicAdd(out + O_LOSS, s * 2.9802322387695312e-08f); // * BETA / NELEM
    }
}

extern "C" void kernel_launch(void* const* d_in, const int* in_sizes, int n_in,
                              void* d_out, int out_size, void* d_ws, size_t ws_size,
                              hipStream_t stream) {
    const float* z_e = (const float*)d_in[0];
    const float* emb = (const float*)d_in[1];
    const float* ema_cs = (const float*)d_in[2];
    const float* ema_w = (const float*)d_in[3];
    float* out = (float*)d_out;
    float* ws = (float*)d_ws;

    float* counts = ws + WS_COUNTS;
    float* enorm = ws + WS_ENORM;
    unsigned long long* row_best = (unsigned long long*)((char*)d_ws + WS_ROWBEST_BYTES);
    int* idxs = (int*)((char*)d_ws + WS_IDX_BYTES);

    _Float16* Zp = (_Float16*)d_out;                        // dead after k_mm
    _Float16* Ep = (_Float16*)((char*)d_out + EP_BYTE_OFF); // dead after k_red
    float* part = (float*)d_out;                            // 8 MB, reuses Zp region after k_mm

    k_init<<<128, 256, 0, stream>>>(ws);
    k_conv_e<<<1024, 256, 0, stream>>>(emb, Ep, enorm);
    k_conv_z<<<dim3(16, 4, 32), 256, 0, stream>>>(z_e, Zp);
    k_mm<<<2048, 256, 0, stream>>>(Zp, Ep, enorm, row_best);
    k_fin_idx<<<128, 256, 0, stream>>>(row_best, idxs, out);
    k_counts<<<32, 256, 0, stream>>>(idxs, counts);
    k_dw<<<dim3(8, 256), 256, 0, stream>>>(z_e, idxs, part);
    k_red<<<dim3(16, 4), 256, 0, stream>>>(part, ema_cs, ema_w, counts, out);
    k_gather<<<dim3(16, 4, 32), 256, 0, stream>>>(z_e, idxs, out);
}

// Round 9
// 240.481 us; speedup vs baseline: 1.1537x; 1.0632x over previous
//
#include <hip/hip_runtime.h>
#include <stdint.h>

#define N_ROWS 32768
#define K_CODES 1024
#define D_DIM 256
#define NELEM 8388608

// ws layout (proven <=1.45MB in prior rounds)
#define WS_COUNTS 0               // float[1024]
#define WS_LOSS 1030              // float[1] accumulator: sum z^2 + sum(c*ne^2 - 2*S*ne)
#define WS_ENORM 263168           // float[1024]
#define WS_ROWBEST_BYTES 1056768  // u64[32768]
#define WS_IDX_BYTES 1318912      // int[32768]

// out offsets (floats)
#define O_ZQ 0
#define O_LOSS 8388608
#define O_IDX 8388609
#define O_EMB 8421377
#define O_CS 8683521
#define O_EMAW 8684545

// scratch carved out of d_out:
//   Zp: seg-major fp16 [64 segs][32768 rows][16B] = bytes [0, 33554432)  (z_q_st region)
//   Ep: seg-major fp16 [64 segs][1024 rows][16B]  = 1 MB at EP_BYTE_OFF  (new_embedding region)
//   part: float [8][256][1024] = 8 MB, reuses bytes [0, 8388608) of the Zp region AFTER k_mm
#define EP_BYTE_OFF 33685520

typedef _Float16 half8 __attribute__((ext_vector_type(8)));
typedef float f32x16 __attribute__((ext_vector_type(16)));

__device__ __forceinline__ unsigned int fenc(float f) {
    unsigned int u = __float_as_uint(f);
    return (u & 0x80000000u) ? ~u : (u | 0x80000000u);
}
__device__ __forceinline__ unsigned long long umin64(unsigned long long a, unsigned long long b) {
    return a < b ? a : b;
}
__device__ __forceinline__ void gll16(const void* g, void* l) {
    __builtin_amdgcn_global_load_lds((const __attribute__((address_space(1))) void*)g,
                                     (__attribute__((address_space(3))) void*)l, 16, 0, 0);
}

__global__ __launch_bounds__(256) void k_init(float* ws) {
    int i = blockIdx.x * 256 + threadIdx.x;
    if (i < 2048) ws[i] = 0.0f;   // counts + loss accumulator
    unsigned long long* rb = (unsigned long long*)((char*)ws + WS_ROWBEST_BYTES);
    if (i < N_ROWS) rb[i] = 0xFFFFFFFFFFFFFFFFull;
}

// emb (1024x256 f32) -> Ep seg-major [64 segs][1024][8 halfs], + enorm
__global__ __launch_bounds__(256) void k_conv_e(const float* __restrict__ emb,
                                                _Float16* __restrict__ Ep,
                                                float* __restrict__ enorm) {
    int k = blockIdx.x, d = threadIdx.x;
    float v = emb[k * 256 + d];
    _Float16 h = (_Float16)v;
    _Float16 l = (_Float16)(v - (float)h);
    int s = d >> 3, sub = d & 7;
    Ep[((size_t)s * 1024 + k) * 8 + sub] = h;
    Ep[((size_t)(32 + s) * 1024 + k) * 8 + sub] = l;
    float sq = v * v;
    #pragma unroll
    for (int off = 32; off >= 1; off >>= 1) sq += __shfl_down(sq, off, 64);
    __shared__ float red[4];
    if ((d & 63) == 0) red[d >> 6] = sq;
    __syncthreads();
    if (d == 0) enorm[k] = (red[0] + red[1]) + (red[2] + red[3]);
}

// z_e[b][d][hw] f32 -> Zp seg-major [64 segs][32768 rows][8 halfs]; + sum z^2 -> lossacc
__global__ __launch_bounds__(256) void k_conv_z(const float* __restrict__ z_e,
                                                _Float16* __restrict__ Zp,
                                                float* __restrict__ lossacc) {
    __shared__ float lt[64 * 68];
    __shared__ float red[4];
    int t = threadIdx.x;
    int hw0 = blockIdx.x * 64, d0 = blockIdx.y * 64, b = blockIdx.z;
    const float* src = z_e + (size_t)b * 262144 + (size_t)d0 * 1024 + hw0;
    int dl = t >> 4, hl = (t & 15) * 4;
    float sq = 0.0f;
    #pragma unroll
    for (int i = 0; i < 4; i++) {
        int d = dl + i * 16;
        float4 v = *(const float4*)(src + (size_t)d * 1024 + hl);
        sq += v.x * v.x + v.y * v.y + v.z * v.z + v.w * v.w;
        lt[(hl + 0) * 68 + d] = v.x;
        lt[(hl + 1) * 68 + d] = v.y;
        lt[(hl + 2) * 68 + d] = v.z;
        lt[(hl + 3) * 68 + d] = v.w;
    }
    __syncthreads();
    int hr = t >> 2, seg = t & 3;
    int n = b * 1024 + hw0 + hr;
    int sg0 = (d0 >> 3) + seg * 2;   // global hi-seg of first 8 halfs
    half8 hi[2], lo[2];
    #pragma unroll
    for (int p = 0; p < 2; p++) {
        #pragma unroll
        for (int j = 0; j < 8; j++) {
            float v = lt[hr * 68 + seg * 16 + p * 8 + j];
            _Float16 h = (_Float16)v;
            hi[p][j] = h;
            lo[p][j] = (_Float16)(v - (float)h);
        }
    }
    *(half8*)(Zp + ((size_t)(sg0 + 0) * 32768 + n) * 8) = hi[0];
    *(half8*)(Zp + ((size_t)(sg0 + 1) * 32768 + n) * 8) = hi[1];
    *(half8*)(Zp + ((size_t)(32 + sg0) * 32768 + n) * 8) = lo[0];
    *(half8*)(Zp + ((size_t)(33 + sg0) * 32768 + n) * 8) = lo[1];
    // block-reduce sum z^2, one atomic per block
    #pragma unroll
    for (int off = 32; off >= 1; off >>= 1) sq += __shfl_down(sq, off, 64);
    if ((t & 63) == 0) red[t >> 6] = sq;
    __syncthreads();
    if (t == 0) atomicAdd(lossacc, (red[0] + red[1]) + (red[2] + red[3]));
}

// fused fp16-split GEMM (3 terms: zh.eh + zl.eh + zh.el) + argmin epilogue.
// block tile 128x128, 4 waves 64x64, mfma 32x32x16 f16, K=64/iter, 12 iters.
// (R6 single-buffer version — dbuf regressed per m99/m100: vmcnt(0) drains at barrier anyway)
__global__ __launch_bounds__(256) void k_mm(const _Float16* __restrict__ Zp,
                                            const _Float16* __restrict__ Ep,
                                            const float* __restrict__ enorm,
                                            unsigned long long* __restrict__ row_best) {
    __shared__ __align__(16) char smem[32768];
    _Float16* Za = (_Float16*)smem;            // [8 segs][128 rows][8 halfs] 16KB
    _Float16* Ea = (_Float16*)(smem + 16384);  // same, for codes
    unsigned long long* slot = (unsigned long long*)smem; // [128][32] after loop

    int t = threadIdx.x;
    int lane = t & 63, wv = t >> 6;
    int b = blockIdx.x;
    int rt = (b & 7) + ((b >> 6) << 3);   // same-Z blocks -> same XCD (assumes %8 round-robin)
    int ct = (b >> 3) & 7;
    int row0 = rt * 128, code0 = ct * 128;

    int wr = wv >> 1, wc = wv & 1;
    int m31 = lane & 31, ko = lane >> 5;

    f32x16 acc[2][2];
    #pragma unroll
    for (int i = 0; i < 2; i++)
        #pragma unroll
        for (int j = 0; j < 2; j++)
            #pragma unroll
            for (int r = 0; r < 16; r++) acc[i][j][r] = 0.0f;

    const char* zgl = (const char*)Zp + ((size_t)(2 * wv) * 32768 + row0 + lane) * 16;
    const char* egl = (const char*)Ep + ((size_t)(2 * wv) * 1024 + code0 + lane) * 16;
    _Float16* zld = Za + 2 * wv * 1024;
    _Float16* eld = Ea + 2 * wv * 1024;

    for (int c = 0; c < 12; c++) {
        int kz = (c < 8) ? c : (c - 8);
        int ge = (c < 4) ? c * 8 : (c < 8) ? (c - 4) * 8 : 32 + (c - 8) * 8;
        const char* zg = zgl + (size_t)kz * 8 * 32768 * 16;
        const char* eg = egl + (size_t)ge * 1024 * 16;
        gll16(zg, zld);
        gll16(zg + 64 * 16, zld + 512);
        gll16(zg + 32768 * 16, zld + 1024);
        gll16(zg + 32768 * 16 + 64 * 16, zld + 1536);
        gll16(eg, eld);
        gll16(eg + 64 * 16, eld + 512);
        gll16(eg + 1024 * 16, eld + 1024);
        gll16(eg + 1024 * 16 + 64 * 16, eld + 1536);
        __syncthreads();
        #pragma unroll
        for (int ks = 0; ks < 4; ks++) {
            int sseg = 2 * ks + ko;
            half8 a0 = *(const half8*)(Za + sseg * 1024 + (wr * 64 + m31) * 8);
            half8 a1 = *(const half8*)(Za + sseg * 1024 + (wr * 64 + 32 + m31) * 8);
            half8 b0 = *(const half8*)(Ea + sseg * 1024 + (wc * 64 + m31) * 8);
            half8 b1 = *(const half8*)(Ea + sseg * 1024 + (wc * 64 + 32 + m31) * 8);
            acc[0][0] = __builtin_amdgcn_mfma_f32_32x32x16_f16(a0, b0, acc[0][0], 0, 0, 0);
            acc[0][1] = __builtin_amdgcn_mfma_f32_32x32x16_f16(a0, b1, acc[0][1], 0, 0, 0);
            acc[1][0] = __builtin_amdgcn_mfma_f32_32x32x16_f16(a1, b0, acc[1][0], 0, 0, 0);
            acc[1][1] = __builtin_amdgcn_mfma_f32_32x32x16_f16(a1, b1, acc[1][1], 0, 0, 0);
        }
        __syncthreads();
    }

    // epilogue: dist = ||e||^2 - 2*dot
    // C/D 32x32 layout: col=lane&31, row=(reg&3)+8*(reg>>2)+4*(lane>>5)
    float en0 = enorm[code0 + wc * 64 + m31];
    float en1 = enorm[code0 + wc * 64 + 32 + m31];
    unsigned int col0 = code0 + wc * 64 + m31;
    unsigned int col1 = col0 + 32;

    if (wc == 0) {
        #pragma unroll
        for (int mt = 0; mt < 2; mt++)
            #pragma unroll
            for (int j = 0; j < 16; j++) {
                int row = wr * 64 + mt * 32 + 4 * ko + (j & 3) + 8 * (j >> 2);
                unsigned long long p0 = ((unsigned long long)fenc(en0 - 2.0f * acc[mt][0][j]) << 32) | col0;
                unsigned long long p1 = ((unsigned long long)fenc(en1 - 2.0f * acc[mt][1][j]) << 32) | col1;
                slot[row * 32 + ((m31 + row) & 31)] = umin64(p0, p1);
            }
    }
    __syncthreads();
    if (wc == 1) {
        #pragma unroll
        for (int mt = 0; mt < 2; mt++)
            #pragma unroll
            for (int j = 0; j < 16; j++) {
                int row = wr * 64 + mt * 32 + 4 * ko + (j & 3) + 8 * (j >> 2);
                unsigned long long p0 = ((unsigned long long)fenc(en0 - 2.0f * acc[mt][0][j]) << 32) | col0;
                unsigned long long p1 = ((unsigned long long)fenc(en1 - 2.0f * acc[mt][1][j]) << 32) | col1;
                atomicMin(&slot[row * 32 + ((m31 + row) & 31)], umin64(p0, p1));
            }
    }
    __syncthreads();
    if (t < 128) {
        unsigned long long m = slot[t * 32 + (t & 31)];
        #pragma unroll
        for (int i = 1; i < 32; i++) m = umin64(m, slot[t * 32 + ((i + t) & 31)]);
        atomicMin(&row_best[row0 + t], m);
    }
}

// finalize indices + histogram (counts) in one pass
__global__ __launch_bounds__(256) void k_fin_idx(const unsigned long long* __restrict__ rb,
                                                 int* __restrict__ idxs,
                                                 float* __restrict__ counts,
                                                 float* __restrict__ out) {
    __shared__ float hist[K_CODES];
    int t = threadIdx.x;
    #pragma unroll
    for (int j = 0; j < 4; j++) hist[j * 256 + t] = 0.0f;
    __syncthreads();
    int i = blockIdx.x * 256 + t;
    int id = (int)(rb[i] & 0xFFFFFFFFull);
    idxs[i] = id;
    out[O_IDX + i] = (float)id;
    atomicAdd(&hist[id], 1.0f);
    __syncthreads();
    #pragma unroll
    for (int j = 0; j < 4; j++) {
        float h = hist[j * 256 + t];
        if (h != 0.0f) atomicAdd(&counts[j * 256 + t], h);
    }
}

// dw partial segment-sum: block (s-chunk, d). float4/int4 loads, LDS acc[1024],
// flush as PLAIN coalesced stores to part[s][d][1024] (no global atomics).
__global__ __launch_bounds__(256) void k_dw(const float* __restrict__ z_e,
                                            const int* __restrict__ idxs,
                                            float* __restrict__ part) {
    __shared__ float acc[K_CODES];
    int t = threadIdx.x;
    int s = blockIdx.x;   // 0..7
    int d = blockIdx.y;   // 0..255
    #pragma unroll
    for (int j = 0; j < 4; j++) acc[j * 256 + t] = 0.0f;
    __syncthreads();
    #pragma unroll
    for (int i = 0; i < 4; i++) {
        int b = s * 4 + i;
        int4 id4 = *(const int4*)(idxs + b * 1024 + t * 4);
        float4 v = *(const float4*)(z_e + (size_t)b * 262144 + (size_t)d * 1024 + t * 4);
        atomicAdd(&acc[id4.x], v.x);
        atomicAdd(&acc[id4.y], v.y);
        atomicAdd(&acc[id4.z], v.z);
        atomicAdd(&acc[id4.w], v.w);
    }
    __syncthreads();
    float* pr = part + ((size_t)s * 256 + d) * 1024;
    #pragma unroll
    for (int j = 0; j < 4; j++) pr[j * 256 + t] = acc[j * 256 + t];
}

// reduce 8 partials + EMA finalize + loss code-terms. block = 64-code x 64-d tile.
// loss terms: sum over (k,d): craw[k]*ne^2 - 2*S*ne  (S = raw segment sum)
__global__ __launch_bounds__(256) void k_red(const float* __restrict__ part,
                                             const float* __restrict__ ema_cs,
                                             const float* __restrict__ ema_w,
                                             const float* __restrict__ counts,
                                             float* __restrict__ lossacc,
                                             float* __restrict__ out) {
    __shared__ float tile[64 * 69];   // [d][k] raw sums, pad 69
    __shared__ float csl[64];
    __shared__ float craw[64];
    __shared__ float red[4];
    int t = threadIdx.x;
    int k0 = blockIdx.x * 64, d0 = blockIdx.y * 64;
    int dr = t >> 4, kc = t & 15;
    float4 sum[4] = {};
    for (int s = 0; s < 8; s++) {
        const float* pb = part + ((size_t)s * 256 + d0) * 1024 + k0 + kc * 4;
        #pragma unroll
        for (int q = 0; q < 4; q++) {
            float4 v = *(const float4*)(pb + (size_t)(dr + 16 * q) * 1024);
            sum[q].x += v.x; sum[q].y += v.y; sum[q].z += v.z; sum[q].w += v.w;
        }
    }
    if (t < 64) {
        float c = counts[k0 + t];
        craw[t] = c;
        csl[t] = 0.99f * ema_cs[k0 + t] + 0.01f * c;
    }
    #pragma unroll
    for (int q = 0; q < 4; q++) {
        float* p = tile + (dr + 16 * q) * 69 + kc * 4;
        p[0] = sum[q].x; p[1] = sum[q].y; p[2] = sum[q].z; p[3] = sum[q].w;
    }
    __syncthreads();
    int kk = t >> 2, dq = t & 3;
    int k = k0 + kk;
    float inv = 1.0f / (csl[kk] + 1e-5f);
    float cr = craw[kk];
    float lterm = 0.0f;
    #pragma unroll
    for (int j4 = 0; j4 < 4; j4++) {
        int dd = dq * 16 + j4 * 4;
        size_t kd = (size_t)k * 256 + d0 + dd;
        float4 w = *(const float4*)(ema_w + kd);
        float s0 = tile[(dd + 0) * 69 + kk];
        float s1 = tile[(dd + 1) * 69 + kk];
        float s2 = tile[(dd + 2) * 69 + kk];
        float s3 = tile[(dd + 3) * 69 + kk];
        float4 nw;
        nw.x = 0.99f * w.x + 0.01f * s0;
        nw.y = 0.99f * w.y + 0.01f * s1;
        nw.z = 0.99f * w.z + 0.01f * s2;
        nw.w = 0.99f * w.w + 0.01f * s3;
        *(float4*)(out + O_EMAW + kd) = nw;
        float4 ne = {nw.x * inv, nw.y * inv, nw.z * inv, nw.w * inv};
        *(float4*)(out + O_EMB + kd) = ne;
        lterm += ne.x * (cr * ne.x - 2.0f * s0);
        lterm += ne.y * (cr * ne.y - 2.0f * s1);
        lterm += ne.z * (cr * ne.z - 2.0f * s2);
        lterm += ne.w * (cr * ne.w - 2.0f * s3);
    }
    if (blockIdx.y == 0 && t < 64) out[O_CS + k0 + t] = csl[t];
    // block-reduce loss term, one atomic per block
    #pragma unroll
    for (int off = 32; off >= 1; off >>= 1) lterm += __shfl_down(lterm, off, 64);
    if ((t & 63) == 0) red[t >> 6] = lterm;
    __syncthreads();
    if (t == 0) atomicAdd(lossacc, (red[0] + red[1]) + (red[2] + red[3]));
}

// broadcast z_q_st = new_embedding[idx] (value of straight-through output).
// No z_e read. block = 64 hw x 64 d; gather coalesced float4 (4 lanes/row),
// write coalesced over hw via LDS transpose. Also writes the final loss.
__global__ __launch_bounds__(256) void k_bcast(const int* __restrict__ idxs,
                                               const float* __restrict__ lossacc,
                                               float* __restrict__ out) {
    __shared__ float lt[64 * 68];
    __shared__ int sid[64];
    int t = threadIdx.x;
    int hw0 = blockIdx.x * 64, d0 = blockIdx.y * 64, b = blockIdx.z;
    if (t < 64) sid[t] = idxs[b * 1024 + hw0 + t];
    __syncthreads();
    int r = t >> 2, c = t & 3;
    const float* nrow = out + O_EMB + (size_t)sid[r] * 256 + d0;
    #pragma unroll
    for (int it = 0; it < 4; it++) {
        int dd = it * 16 + c * 4;
        float4 q = *(const float4*)(nrow + dd);
        float* p = lt + r * 68 + dd;
        p[0] = q.x; p[1] = q.y; p[2] = q.z; p[3] = q.w;
    }
    __syncthreads();
    int dl = t >> 4, hl = (t & 15) * 4;
    float* dst = out + O_ZQ + (size_t)b * 262144 + (size_t)d0 * 1024 + hw0;
    #pragma unroll
    for (int i = 0; i < 4; i++) {
        int d = dl + i * 16;
        float4 w;
        w.x = lt[(hl + 0) * 68 + d];
        w.y = lt[(hl + 1) * 68 + d];
        w.z = lt[(hl + 2) * 68 + d];
        w.w = lt[(hl + 3) * 68 + d];
        *(float4*)(dst + (size_t)d * 1024 + hl) = w;
    }
    if (blockIdx.x == 0 && blockIdx.y == 0 && blockIdx.z == 0 && t == 0)
        out[O_LOSS] = lossacc[0] * 2.9802322387695312e-08f;   // * BETA / NELEM
}

extern "C" void kernel_launch(void* const* d_in, const int* in_sizes, int n_in,
                              void* d_out, int out_size, void* d_ws, size_t ws_size,
                              hipStream_t stream) {
    const float* z_e = (const float*)d_in[0];
    const float* emb = (const float*)d_in[1];
    const float* ema_cs = (const float*)d_in[2];
    const float* ema_w = (const float*)d_in[3];
    float* out = (float*)d_out;
    float* ws = (float*)d_ws;

    float* counts = ws + WS_COUNTS;
    float* lossacc = ws + WS_LOSS;
    float* enorm = ws + WS_ENORM;
    unsigned long long* row_best = (unsigned long long*)((char*)d_ws + WS_ROWBEST_BYTES);
    int* idxs = (int*)((char*)d_ws + WS_IDX_BYTES);

    _Float16* Zp = (_Float16*)d_out;                        // dead after k_mm
    _Float16* Ep = (_Float16*)((char*)d_out + EP_BYTE_OFF); // dead after k_red
    float* part = (float*)d_out;                            // 8 MB, reuses Zp region after k_mm

    k_init<<<128, 256, 0, stream>>>(ws);
    k_conv_e<<<1024, 256, 0, stream>>>(emb, Ep, enorm);
    k_conv_z<<<dim3(16, 4, 32), 256, 0, stream>>>(z_e, Zp, lossacc);
    k_mm<<<2048, 256, 0, stream>>>(Zp, Ep, enorm, row_best);
    k_fin_idx<<<128, 256, 0, stream>>>(row_best, idxs, counts, out);
    k_dw<<<dim3(8, 256), 256, 0, stream>>>(z_e, idxs, part);
    k_red<<<dim3(16, 4), 256, 0, stream>>>(part, ema_cs, ema_w, counts, lossacc, out);
    k_bcast<<<dim3(16, 4, 32), 256, 0, stream>>>(idxs, lossacc, out);
}